// Round 2
// baseline (371.783 us; speedup 1.0000x reference)
//
#include <hip/hip_runtime.h>

#define D 64

// ---------- CSR build ----------
__global__ __launch_bounds__(256) void hist_kernel(const int* __restrict__ dst,
                                                   int* __restrict__ cnt, int E) {
    int e = blockIdx.x * 256 + threadIdx.x;
    if (e < E) atomicAdd(&cnt[dst[e]], 1);
}

// block b reduces cnt[b*1024 .. +1024) -> bsum[b]
__global__ __launch_bounds__(256) void scan_a_kernel(const int* __restrict__ cnt,
                                                     int* __restrict__ bsum, int N) {
    int base = blockIdx.x * 1024 + threadIdx.x * 4;
    int s = 0;
    #pragma unroll
    for (int q = 0; q < 4; ++q) { int i = base + q; if (i < N) s += cnt[i]; }
    for (int off = 32; off > 0; off >>= 1) s += __shfl_down(s, off, 64);
    __shared__ int wsum[4];
    int lane = threadIdx.x & 63, w = threadIdx.x >> 6;
    if (lane == 0) wsum[w] = s;
    __syncthreads();
    if (threadIdx.x == 0) bsum[blockIdx.x] = wsum[0] + wsum[1] + wsum[2] + wsum[3];
}

// single wave: exclusive scan of bsum[NB], NB <= 64
__global__ __launch_bounds__(64) void scan_b_kernel(int* __restrict__ bsum, int NB) {
    int lane = threadIdx.x;
    int v = (lane < NB) ? bsum[lane] : 0;
    int s = v;
    for (int off = 1; off < 64; off <<= 1) {
        int u = __shfl_up(s, off, 64);
        if (lane >= off) s += u;
    }
    if (lane < NB) bsum[lane] = s - v;   // exclusive
}

// block b: exclusive-scan its 1024 counts + bsum[b] -> row_start[i+1] = inclusive prefix
__global__ __launch_bounds__(256) void scan_c_kernel(const int* __restrict__ cnt,
                                                     const int* __restrict__ bsum,
                                                     int* __restrict__ row_start, int N) {
    int t = threadIdx.x;
    int base = blockIdx.x * 1024 + t * 4;
    int v[4]; int s = 0;
    #pragma unroll
    for (int q = 0; q < 4; ++q) { int i = base + q; v[q] = (i < N) ? cnt[i] : 0; s += v[q]; }
    int sc = s;
    int lane = t & 63, w = t >> 6;
    for (int off = 1; off < 64; off <<= 1) {
        int u = __shfl_up(sc, off, 64);
        if (lane >= off) sc += u;
    }
    __shared__ int wtot[4];
    if (lane == 63) wtot[w] = sc;
    __syncthreads();
    int woff = 0;
    for (int i = 0; i < 4; ++i) if (i < w) woff += wtot[i];
    int run = bsum[blockIdx.x] + woff + (sc - s);  // exclusive prefix before this thread's 4 elems
    if (blockIdx.x == 0 && t == 0) row_start[0] = 0;
    #pragma unroll
    for (int q = 0; q < 4; ++q) {
        int i = base + q;
        run += v[q];
        if (i < N) row_start[i + 1] = run;
    }
}

// scatter edge records {src, w*out_deg[src]} into CSR buckets
__global__ __launch_bounds__(256) void fill_kernel(const int* __restrict__ src, const int* __restrict__ dst,
                                                   const float* __restrict__ ew, const float* __restrict__ odeg,
                                                   const int* __restrict__ row_start, int* __restrict__ cur,
                                                   int2* __restrict__ rec, int E) {
    int e = blockIdx.x * 256 + threadIdx.x;
    if (e >= E) return;
    int d = dst[e], s = src[e];
    float w = ew[e] * odeg[s];
    int pos = row_start[d] + atomicAdd(&cur[d], 1);
    rec[pos] = make_int2(s, __float_as_int(w));
}

// ---------- fused gather + GEMM epilogue ----------
// block = 64 nodes. Phase 1: wave w gathers rows [16w,16w+16), lane = feature k,
// X = embed + (sum_edges w*embed[src]) * in_deg, stored XOR-swizzled in LDS.
// Phase 2: 4x4-register-tile GEMM out = leaky_relu(X @ W^T + b), b128 LDS reads,
// swizzle (chunk q of row r at q ^ (r>>2)) makes all reads conflict-free.
__global__ __launch_bounds__(256) void fused_kernel(const float* __restrict__ embed,
                                                    const float* __restrict__ in_deg,
                                                    const int* __restrict__ row_start,
                                                    const int2* __restrict__ rec,
                                                    const float* __restrict__ W,
                                                    const float* __restrict__ b,
                                                    float* __restrict__ out, int N) {
    __shared__ float Xs[64 * 64];
    __shared__ float Ws[64 * 64];
    const int t = threadIdx.x;
    const int lane = t & 63;
    const int w = t >> 6;

    // stage W (row c, col k) swizzled
    for (int idx = t; idx < 4096; idx += 256) {
        int c = idx >> 6, k = idx & 63;
        int kk = (k & 3) + ((((k >> 2)) ^ (c >> 2)) << 2);
        Ws[c * 64 + kk] = W[idx];
    }

    const int n0 = blockIdx.x * 64;
    for (int i = 0; i < 16; ++i) {
        int r = w * 16 + i;
        int n = n0 + r;
        float x = 0.f;
        if (n < N) {                       // uniform branch (n lane-independent)
            float acc = 0.f;
            int beg = row_start[n], end = row_start[n + 1];
            beg = __builtin_amdgcn_readfirstlane(beg);
            end = __builtin_amdgcn_readfirstlane(end);
            int j = beg;
            for (; j + 4 <= end; j += 4) {
                int2 e0 = rec[j], e1 = rec[j + 1], e2 = rec[j + 2], e3 = rec[j + 3];
                float v0 = embed[(size_t)e0.x * D + lane];
                float v1 = embed[(size_t)e1.x * D + lane];
                float v2 = embed[(size_t)e2.x * D + lane];
                float v3 = embed[(size_t)e3.x * D + lane];
                acc += __int_as_float(e0.y) * v0;
                acc += __int_as_float(e1.y) * v1;
                acc += __int_as_float(e2.y) * v2;
                acc += __int_as_float(e3.y) * v3;
            }
            for (; j < end; ++j) {
                int2 e0 = rec[j];
                acc += __int_as_float(e0.y) * embed[(size_t)e0.x * D + lane];
            }
            x = embed[(size_t)n * D + lane] + acc * in_deg[n];
        }
        int kk = (lane & 3) + ((((lane >> 2)) ^ (r >> 2)) << 2);
        Xs[r * 64 + kk] = x;
    }
    __syncthreads();

    // GEMM: thread (tr, tc) owns rows r0..r0+3, cols c0..c0+3
    const int tr = t >> 4, tc = t & 15;
    const int r0 = tr << 2, c0 = tc << 2;
    float acc[4][4];
    #pragma unroll
    for (int i = 0; i < 4; ++i)
        #pragma unroll
        for (int j = 0; j < 4; ++j) acc[i][j] = 0.f;

    #pragma unroll
    for (int qb = 0; qb < 16; ++qb) {
        const int qx = (qb ^ tr) << 2;   // (r0+i)>>2 == tr for i<4
        const int qw = (qb ^ tc) << 2;   // (c0+j)>>2 == tc for j<4
        float4 xv[4], wv[4];
        #pragma unroll
        for (int i = 0; i < 4; ++i) xv[i] = *(const float4*)&Xs[(r0 + i) * 64 + qx];
        #pragma unroll
        for (int j = 0; j < 4; ++j) wv[j] = *(const float4*)&Ws[(c0 + j) * 64 + qw];
        #pragma unroll
        for (int i = 0; i < 4; ++i)
            #pragma unroll
            for (int j = 0; j < 4; ++j)
                acc[i][j] += xv[i].x * wv[j].x + xv[i].y * wv[j].y
                           + xv[i].z * wv[j].z + xv[i].w * wv[j].w;
    }

    const float4 bv = *(const float4*)&b[c0];
    #pragma unroll
    for (int i = 0; i < 4; ++i) {
        int n = n0 + r0 + i;
        if (n < N) {
            float4 o;
            float vx = acc[i][0] + bv.x; o.x = vx > 0.f ? vx : 0.01f * vx;
            float vy = acc[i][1] + bv.y; o.y = vy > 0.f ? vy : 0.01f * vy;
            float vz = acc[i][2] + bv.z; o.z = vz > 0.f ? vz : 0.01f * vz;
            float vw = acc[i][3] + bv.w; o.w = vw > 0.f ? vw : 0.01f * vw;
            *(float4*)&out[(size_t)n * D + c0] = o;
        }
    }
}

extern "C" void kernel_launch(void* const* d_in, const int* in_sizes, int n_in,
                              void* d_out, int out_size, void* d_ws, size_t ws_size,
                              hipStream_t stream) {
    const float* embed = (const float*)d_in[0];
    const int*   src   = (const int*)  d_in[1];
    const int*   dst   = (const int*)  d_in[2];
    const float* ew    = (const float*)d_in[3];
    const float* odeg  = (const float*)d_in[4];
    const float* ideg  = (const float*)d_in[5];
    const float* W     = (const float*)d_in[6];
    const float* b     = (const float*)d_in[7];
    float* out = (float*)d_out;

    const int N = in_sizes[0] / D;   // 50000
    const int E = in_sizes[1];       // 800000
    const int NB = (N + 1023) / 1024;  // 49 (<= 64 required by scan_b)

    // ws layout (4B units): cnt[0,50048) cur[50048,100096) bsum[100096,100160)
    //                       row_start[100160,150162) rec @ byte 601856 (8B aligned)
    int* cnt       = (int*)d_ws;
    int* cur       = cnt + 50048;
    int* bsum      = cnt + 100096;
    int* row_start = cnt + 100160;
    int2* rec      = (int2*)((char*)d_ws + 601856);

    hipMemsetAsync(cnt, 0, (size_t)100096 * 4, stream);  // zeroes cnt + cur

    hist_kernel  <<<(E + 255) / 256, 256, 0, stream>>>(dst, cnt, E);
    scan_a_kernel<<<NB, 256, 0, stream>>>(cnt, bsum, N);
    scan_b_kernel<<<1, 64, 0, stream>>>(bsum, NB);
    scan_c_kernel<<<NB, 256, 0, stream>>>(cnt, bsum, row_start, N);
    fill_kernel  <<<(E + 255) / 256, 256, 0, stream>>>(src, dst, ew, odeg, row_start, cur, rec, E);
    fused_kernel <<<(N + 63) / 64, 256, 0, stream>>>(embed, ideg, row_start, rec, W, b, out, N);
}

// Round 3
// 238.777 us; speedup vs baseline: 1.5570x; 1.5570x over previous
//
#include <hip/hip_runtime.h>

#define D 64

// ---------- CSR build ----------
__global__ __launch_bounds__(256) void hist_kernel(const int* __restrict__ dst,
                                                   int* __restrict__ cnt, int E) {
    int e = blockIdx.x * 256 + threadIdx.x;
    if (e < E) atomicAdd(&cnt[dst[e]], 1);
}

// block b reduces cnt[b*1024 .. +1024) -> bsum[b]
__global__ __launch_bounds__(256) void scan_a_kernel(const int* __restrict__ cnt,
                                                     int* __restrict__ bsum, int N) {
    int base = blockIdx.x * 1024 + threadIdx.x * 4;
    int s = 0;
    #pragma unroll
    for (int q = 0; q < 4; ++q) { int i = base + q; if (i < N) s += cnt[i]; }
    for (int off = 32; off > 0; off >>= 1) s += __shfl_down(s, off, 64);
    __shared__ int wsum[4];
    int lane = threadIdx.x & 63, w = threadIdx.x >> 6;
    if (lane == 0) wsum[w] = s;
    __syncthreads();
    if (threadIdx.x == 0) bsum[blockIdx.x] = wsum[0] + wsum[1] + wsum[2] + wsum[3];
}

// single wave: exclusive scan of bsum[NB], NB <= 64
__global__ __launch_bounds__(64) void scan_b_kernel(int* __restrict__ bsum, int NB) {
    int lane = threadIdx.x;
    int v = (lane < NB) ? bsum[lane] : 0;
    int s = v;
    for (int off = 1; off < 64; off <<= 1) {
        int u = __shfl_up(s, off, 64);
        if (lane >= off) s += u;
    }
    if (lane < NB) bsum[lane] = s - v;   // exclusive
}

// block b: exclusive-scan its 1024 counts + bsum[b] -> row_start[i+1] = inclusive prefix
__global__ __launch_bounds__(256) void scan_c_kernel(const int* __restrict__ cnt,
                                                     const int* __restrict__ bsum,
                                                     int* __restrict__ row_start, int N) {
    int t = threadIdx.x;
    int base = blockIdx.x * 1024 + t * 4;
    int v[4]; int s = 0;
    #pragma unroll
    for (int q = 0; q < 4; ++q) { int i = base + q; v[q] = (i < N) ? cnt[i] : 0; s += v[q]; }
    int sc = s;
    int lane = t & 63, w = t >> 6;
    for (int off = 1; off < 64; off <<= 1) {
        int u = __shfl_up(sc, off, 64);
        if (lane >= off) sc += u;
    }
    __shared__ int wtot[4];
    if (lane == 63) wtot[w] = sc;
    __syncthreads();
    int woff = 0;
    for (int i = 0; i < 4; ++i) if (i < w) woff += wtot[i];
    int run = bsum[blockIdx.x] + woff + (sc - s);
    if (blockIdx.x == 0 && t == 0) row_start[0] = 0;
    #pragma unroll
    for (int q = 0; q < 4; ++q) {
        int i = base + q;
        run += v[q];
        if (i < N) row_start[i + 1] = run;
    }
}

// scatter edge records {src, w*out_deg[src]} into CSR buckets
__global__ __launch_bounds__(256) void fill_kernel(const int* __restrict__ src, const int* __restrict__ dst,
                                                   const float* __restrict__ ew, const float* __restrict__ odeg,
                                                   const int* __restrict__ row_start, int* __restrict__ cur,
                                                   int2* __restrict__ rec, int E) {
    int e = blockIdx.x * 256 + threadIdx.x;
    if (e >= E) return;
    int d = dst[e], s = src[e];
    float w = ew[e] * odeg[s];
    int pos = row_start[d] + atomicAdd(&cur[d], 1);
    rec[pos] = make_int2(s, __float_as_int(w));
}

// ---------- gather: one wave per node, lane = feature ----------
// X[n] = embed[n] + (sum_e w_e * embed[src_e]) * in_deg[n]
__global__ __launch_bounds__(256) void gather_kernel(const float* __restrict__ embed,
                                                     const float* __restrict__ in_deg,
                                                     const int* __restrict__ row_start,
                                                     const int2* __restrict__ rec,
                                                     float* __restrict__ X, int N) {
    const int lane = threadIdx.x & 63;
    const int n = blockIdx.x * 4 + (threadIdx.x >> 6);
    if (n >= N) return;
    const int beg = __builtin_amdgcn_readfirstlane(row_start[n]);
    const int end = __builtin_amdgcn_readfirstlane(row_start[n + 1]);

    float acc = 0.f;
    for (int c0 = beg; c0 < end; c0 += 64) {
        const int cnt = min(64, end - c0);
        int rs = 0, rw = 0;                      // lanes >= cnt: src=0, w=0 (padding)
        if (lane < cnt) { int2 r = rec[c0 + lane]; rs = r.x; rw = r.y; }
        const int cpad = (cnt + 7) & ~7;
        for (int j = 0; j < cpad; j += 8) {      // j uniform -> readlane legal
            float v[8], wf[8];
            #pragma unroll
            for (int k = 0; k < 8; ++k) {
                int s = __builtin_amdgcn_readlane(rs, j + k);
                wf[k] = __int_as_float(__builtin_amdgcn_readlane(rw, j + k));
                v[k] = embed[(size_t)s * D + lane];   // 8 independent coalesced gathers
            }
            #pragma unroll
            for (int k = 0; k < 8; ++k) acc += wf[k] * v[k];
        }
    }
    const float x = embed[(size_t)n * D + lane] + acc * in_deg[n];
    X[(size_t)n * D + lane] = x;
}

// ---------- GEMM epilogue: out = leaky_relu(X @ W^T + b) ----------
__global__ __launch_bounds__(256) void gemm_kernel(const float* __restrict__ X,
                                                   const float* __restrict__ W,
                                                   const float* __restrict__ b,
                                                   float* __restrict__ out, int N) {
    __shared__ float Xs[64 * 64];
    __shared__ float Ws[64 * 64];
    const int t = threadIdx.x;
    const int n0 = blockIdx.x * 64;

    // stage X and W, XOR-swizzled (chunk q of row r stored at q ^ (r>>2)), float4
    for (int idx = t; idx < 1024; idx += 256) {
        const int r = idx >> 4, q = idx & 15;
        float4 xv = make_float4(0.f, 0.f, 0.f, 0.f);
        if (n0 + r < N) xv = *(const float4*)&X[(size_t)(n0 + r) * D + q * 4];
        *(float4*)&Xs[r * 64 + ((q ^ (r >> 2)) << 2)] = xv;
        const float4 wv = *(const float4*)&W[idx * 4];   // row c=r, chunk q
        *(float4*)&Ws[r * 64 + ((q ^ (r >> 2)) << 2)] = wv;
    }
    __syncthreads();

    // thread (tr, tc) owns rows r0..r0+3, cols c0..c0+3
    const int tr = t >> 4, tc = t & 15;
    const int r0 = tr << 2, c0 = tc << 2;
    float acc[4][4];
    #pragma unroll
    for (int i = 0; i < 4; ++i)
        #pragma unroll
        for (int j = 0; j < 4; ++j) acc[i][j] = 0.f;

    #pragma unroll
    for (int qb = 0; qb < 16; ++qb) {
        const int qx = (qb ^ tr) << 2;   // (r0+i)>>2 == tr
        const int qw = (qb ^ tc) << 2;   // (c0+j)>>2 == tc
        float4 xv[4], wv[4];
        #pragma unroll
        for (int i = 0; i < 4; ++i) xv[i] = *(const float4*)&Xs[(r0 + i) * 64 + qx];
        #pragma unroll
        for (int j = 0; j < 4; ++j) wv[j] = *(const float4*)&Ws[(c0 + j) * 64 + qw];
        #pragma unroll
        for (int i = 0; i < 4; ++i)
            #pragma unroll
            for (int j = 0; j < 4; ++j)
                acc[i][j] += xv[i].x * wv[j].x + xv[i].y * wv[j].y
                           + xv[i].z * wv[j].z + xv[i].w * wv[j].w;
    }

    const float4 bv = *(const float4*)&b[c0];
    #pragma unroll
    for (int i = 0; i < 4; ++i) {
        const int n = n0 + r0 + i;
        if (n < N) {
            float4 o;
            float vx = acc[i][0] + bv.x; o.x = vx > 0.f ? vx : 0.01f * vx;
            float vy = acc[i][1] + bv.y; o.y = vy > 0.f ? vy : 0.01f * vy;
            float vz = acc[i][2] + bv.z; o.z = vz > 0.f ? vz : 0.01f * vz;
            float vw = acc[i][3] + bv.w; o.w = vw > 0.f ? vw : 0.01f * vw;
            *(float4*)&out[(size_t)n * D + c0] = o;
        }
    }
}

extern "C" void kernel_launch(void* const* d_in, const int* in_sizes, int n_in,
                              void* d_out, int out_size, void* d_ws, size_t ws_size,
                              hipStream_t stream) {
    const float* embed = (const float*)d_in[0];
    const int*   src   = (const int*)  d_in[1];
    const int*   dst   = (const int*)  d_in[2];
    const float* ew    = (const float*)d_in[3];
    const float* odeg  = (const float*)d_in[4];
    const float* ideg  = (const float*)d_in[5];
    const float* W     = (const float*)d_in[6];
    const float* b     = (const float*)d_in[7];
    float* out = (float*)d_out;

    const int N = in_sizes[0] / D;     // 50000
    const int E = in_sizes[1];         // 800000
    const int NB = (N + 1023) / 1024;  // 49 (<= 64 for scan_b)

    // ws layout (4B units): cnt[0,50048) cur[50048,100096) bsum[100096,100160)
    //                       row_start[100160,150162)
    // rec  @ byte 1048576  (E*8  = 6.4 MB)
    // X    @ byte 16777216 (N*D*4 = 12.8 MB)
    int* cnt       = (int*)d_ws;
    int* cur       = cnt + 50048;
    int* bsum      = cnt + 100096;
    int* row_start = cnt + 100160;
    int2*  rec = (int2*) ((char*)d_ws + (1u << 20));
    float* X   = (float*)((char*)d_ws + (1u << 24));

    hipMemsetAsync(cnt, 0, (size_t)100096 * 4, stream);  // zeroes cnt + cur

    hist_kernel  <<<(E + 255) / 256, 256, 0, stream>>>(dst, cnt, E);
    scan_a_kernel<<<NB, 256, 0, stream>>>(cnt, bsum, N);
    scan_b_kernel<<<1, 64, 0, stream>>>(bsum, NB);
    scan_c_kernel<<<NB, 256, 0, stream>>>(cnt, bsum, row_start, N);
    fill_kernel  <<<(E + 255) / 256, 256, 0, stream>>>(src, dst, ew, odeg, row_start, cur, rec, E);
    gather_kernel<<<(N + 3) / 4, 256, 0, stream>>>(embed, ideg, row_start, rec, X, N);
    gemm_kernel  <<<(N + 63) / 64, 256, 0, stream>>>(X, W, b, out, N);
}

// Round 4
// 212.829 us; speedup vs baseline: 1.7469x; 1.1219x over previous
//
#include <hip/hip_runtime.h>

#define D 64

// ---------- CSR build ----------
__global__ __launch_bounds__(256) void hist_kernel(const int* __restrict__ dst,
                                                   int* __restrict__ cnt, int E) {
    int e = blockIdx.x * 256 + threadIdx.x;
    if (e < E) atomicAdd(&cnt[dst[e]], 1);
}

// block b reduces cnt[b*1024 .. +1024) -> bsum[b]
__global__ __launch_bounds__(256) void scan_a_kernel(const int* __restrict__ cnt,
                                                     int* __restrict__ bsum, int N) {
    int base = blockIdx.x * 1024 + threadIdx.x * 4;
    int s = 0;
    #pragma unroll
    for (int q = 0; q < 4; ++q) { int i = base + q; if (i < N) s += cnt[i]; }
    for (int off = 32; off > 0; off >>= 1) s += __shfl_down(s, off, 64);
    __shared__ int wsum[4];
    int lane = threadIdx.x & 63, w = threadIdx.x >> 6;
    if (lane == 0) wsum[w] = s;
    __syncthreads();
    if (threadIdx.x == 0) bsum[blockIdx.x] = wsum[0] + wsum[1] + wsum[2] + wsum[3];
}

// single wave: exclusive scan of bsum[NB], NB <= 64
__global__ __launch_bounds__(64) void scan_b_kernel(int* __restrict__ bsum, int NB) {
    int lane = threadIdx.x;
    int v = (lane < NB) ? bsum[lane] : 0;
    int s = v;
    for (int off = 1; off < 64; off <<= 1) {
        int u = __shfl_up(s, off, 64);
        if (lane >= off) s += u;
    }
    if (lane < NB) bsum[lane] = s - v;   // exclusive
}

// block b: exclusive-scan its 1024 counts + bsum[b] -> row_start[i+1] = inclusive prefix
__global__ __launch_bounds__(256) void scan_c_kernel(const int* __restrict__ cnt,
                                                     const int* __restrict__ bsum,
                                                     int* __restrict__ row_start, int N) {
    int t = threadIdx.x;
    int base = blockIdx.x * 1024 + t * 4;
    int v[4]; int s = 0;
    #pragma unroll
    for (int q = 0; q < 4; ++q) { int i = base + q; v[q] = (i < N) ? cnt[i] : 0; s += v[q]; }
    int sc = s;
    int lane = t & 63, w = t >> 6;
    for (int off = 1; off < 64; off <<= 1) {
        int u = __shfl_up(sc, off, 64);
        if (lane >= off) sc += u;
    }
    __shared__ int wtot[4];
    if (lane == 63) wtot[w] = sc;
    __syncthreads();
    int woff = 0;
    for (int i = 0; i < 4; ++i) if (i < w) woff += wtot[i];
    int run = bsum[blockIdx.x] + woff + (sc - s);
    if (blockIdx.x == 0 && t == 0) row_start[0] = 0;
    #pragma unroll
    for (int q = 0; q < 4; ++q) {
        int i = base + q;
        run += v[q];
        if (i < N) row_start[i + 1] = run;
    }
}

// scatter edge records {src, w*out_deg[src]} into CSR buckets
__global__ __launch_bounds__(256) void fill_kernel(const int* __restrict__ src, const int* __restrict__ dst,
                                                   const float* __restrict__ ew, const float* __restrict__ odeg,
                                                   const int* __restrict__ row_start, int* __restrict__ cur,
                                                   int2* __restrict__ rec, int E) {
    int e = blockIdx.x * 256 + threadIdx.x;
    if (e >= E) return;
    int d = dst[e], s = src[e];
    float w = ew[e] * odeg[s];
    int pos = row_start[d] + atomicAdd(&cur[d], 1);
    rec[pos] = make_int2(s, __float_as_int(w));
}

// ---------- fused gather + GEMM ----------
// Block = 64 nodes, 4 waves. Phase 1: wave w gathers nodes [16w,16w+16)
// (lane = feature k) with lane-parallel CSR-record prefetch + readlane
// broadcast; X stored XOR-swizzled in LDS. Phase 2: conflict-free 4x4
// register-tile GEMM out = leaky_relu(X @ W^T + b).
// __launch_bounds__(256,4): VGPR<=128 -> 4 blocks/CU (16 waves/CU).
__global__ __launch_bounds__(256, 4) void fused_kernel(const float* __restrict__ embed,
                                                       const float* __restrict__ in_deg,
                                                       const int* __restrict__ row_start,
                                                       const int2* __restrict__ rec,
                                                       const float* __restrict__ W,
                                                       const float* __restrict__ b,
                                                       float* __restrict__ out, int N) {
    __shared__ float Xs[64 * 64];
    __shared__ float Ws[64 * 64];
    const int t = threadIdx.x;
    const int lane = t & 63;
    const int w = t >> 6;
    const int n0 = blockIdx.x * 64;

    // stage W swizzled: chunk q of row c stored at chunk position q ^ (c>>2)
    for (int idx = t; idx < 1024; idx += 256) {
        const int c = idx >> 4, q = idx & 15;
        const float4 wv = *(const float4*)&W[idx * 4];
        *(float4*)&Ws[c * 64 + ((q ^ (c >> 2)) << 2)] = wv;
    }

    // gather phase: wave w handles rows r = 16w .. 16w+15
    for (int i = 0; i < 16; ++i) {
        const int r = w * 16 + i;
        const int n = n0 + r;
        float x = 0.f;
        if (n < N) {                      // wave-uniform branch
            const int beg = __builtin_amdgcn_readfirstlane(row_start[n]);
            const int end = __builtin_amdgcn_readfirstlane(row_start[n + 1]);
            float acc = 0.f;
            for (int c0 = beg; c0 < end; c0 += 64) {
                const int cnt = min(64, end - c0);
                int rs = 0, rw = 0;       // padding lanes: src=0, w=0
                if (lane < cnt) { int2 rr = rec[c0 + lane]; rs = rr.x; rw = rr.y; }
                const int cpad = (cnt + 7) & ~7;
                for (int j = 0; j < cpad; j += 8) {   // j uniform -> readlane legal
                    float v[8], wf[8];
                    #pragma unroll
                    for (int k = 0; k < 8; ++k) {
                        int s = __builtin_amdgcn_readlane(rs, j + k);
                        wf[k] = __int_as_float(__builtin_amdgcn_readlane(rw, j + k));
                        v[k] = embed[(size_t)s * D + lane];  // independent coalesced gathers
                    }
                    #pragma unroll
                    for (int k = 0; k < 8; ++k) acc += wf[k] * v[k];
                }
            }
            x = embed[(size_t)n * D + lane] + acc * in_deg[n];
        }
        // swizzled store: conflict-free (permutation within the row)
        Xs[r * 64 + (((lane >> 2) ^ (r >> 2)) << 2) + (lane & 3)] = x;
    }
    __syncthreads();

    // GEMM phase: thread (tr,tc) owns rows r0..r0+3, cols c0..c0+3
    const int tr = t >> 4, tc = t & 15;
    const int r0 = tr << 2, c0 = tc << 2;
    float acc[4][4];
    #pragma unroll
    for (int i = 0; i < 4; ++i)
        #pragma unroll
        for (int j = 0; j < 4; ++j) acc[i][j] = 0.f;

    #pragma unroll 4
    for (int qb = 0; qb < 16; ++qb) {
        const int qx = (qb ^ tr) << 2;   // (r0+i)>>2 == tr
        const int qw = (qb ^ tc) << 2;   // (c0+j)>>2 == tc
        float4 xv[4], wv[4];
        #pragma unroll
        for (int i = 0; i < 4; ++i) xv[i] = *(const float4*)&Xs[(r0 + i) * 64 + qx];
        #pragma unroll
        for (int j = 0; j < 4; ++j) wv[j] = *(const float4*)&Ws[(c0 + j) * 64 + qw];
        #pragma unroll
        for (int i = 0; i < 4; ++i)
            #pragma unroll
            for (int j = 0; j < 4; ++j)
                acc[i][j] += xv[i].x * wv[j].x + xv[i].y * wv[j].y
                           + xv[i].z * wv[j].z + xv[i].w * wv[j].w;
    }

    const float4 bv = *(const float4*)&b[c0];
    #pragma unroll
    for (int i = 0; i < 4; ++i) {
        const int n = n0 + r0 + i;
        if (n < N) {
            float4 o;
            float vx = acc[i][0] + bv.x; o.x = vx > 0.f ? vx : 0.01f * vx;
            float vy = acc[i][1] + bv.y; o.y = vy > 0.f ? vy : 0.01f * vy;
            float vz = acc[i][2] + bv.z; o.z = vz > 0.f ? vz : 0.01f * vz;
            float vw = acc[i][3] + bv.w; o.w = vw > 0.f ? vw : 0.01f * vw;
            *(float4*)&out[(size_t)n * D + c0] = o;
        }
    }
}

extern "C" void kernel_launch(void* const* d_in, const int* in_sizes, int n_in,
                              void* d_out, int out_size, void* d_ws, size_t ws_size,
                              hipStream_t stream) {
    const float* embed = (const float*)d_in[0];
    const int*   src   = (const int*)  d_in[1];
    const int*   dst   = (const int*)  d_in[2];
    const float* ew    = (const float*)d_in[3];
    const float* odeg  = (const float*)d_in[4];
    const float* ideg  = (const float*)d_in[5];
    const float* W     = (const float*)d_in[6];
    const float* b     = (const float*)d_in[7];
    float* out = (float*)d_out;

    const int N = in_sizes[0] / D;     // 50000
    const int E = in_sizes[1];         // 800000
    const int NB = (N + 1023) / 1024;  // 49 (<= 64 for scan_b)

    // ws layout (4B units): cnt[0,50048) cur[50048,100096) bsum[100096,100160)
    //                       row_start[100160,150162); rec @ byte 1 MB (E*8 = 6.4 MB)
    int* cnt       = (int*)d_ws;
    int* cur       = cnt + 50048;
    int* bsum      = cnt + 100096;
    int* row_start = cnt + 100160;
    int2* rec = (int2*)((char*)d_ws + (1u << 20));

    hipMemsetAsync(cnt, 0, (size_t)100096 * 4, stream);  // zeroes cnt + cur

    hist_kernel  <<<(E + 255) / 256, 256, 0, stream>>>(dst, cnt, E);
    scan_a_kernel<<<NB, 256, 0, stream>>>(cnt, bsum, N);
    scan_b_kernel<<<1, 64, 0, stream>>>(bsum, NB);
    scan_c_kernel<<<NB, 256, 0, stream>>>(cnt, bsum, row_start, N);
    fill_kernel  <<<(E + 255) / 256, 256, 0, stream>>>(src, dst, ew, odeg, row_start, cur, rec, E);
    fused_kernel <<<(N + 63) / 64, 256, 0, stream>>>(embed, ideg, row_start, rec, W, b, out, N);
}